// Round 7
// baseline (18362.296 us; speedup 1.0000x reference)
//
#include <hip/hip_runtime.h>
#include <stdint.h>

// VanillaRNN — Round 16: batch-major waves + scalar-pipe W + flag exchange.
//
// R15 (12.64 ms, WIN): persistent-W clusters. Remaining cost: (a) LDS return
// bus — 8 B/FMA (w + state) = 10,240 cyc/CU/step; (b) exchange — 16 serialized
// same-line fetch_adds + poll. R16: lane = batch, wave = column -> w is
// wave-uniform: streamed via s_load (SMEM pipe, K$) from a per-WG-transposed
// W^T slice in d_ws; FMA is v_fmac_f32 v,s,v. LDS carries ONLY state (4 B/FMA
// = 5,120 cyc/CU). Exchange: per-rank monotonic flag release-stores, 64-lane
// parallel wait + 1 acquire; xh phase (no h dependency) runs before the wait.
// t=0: hh chain over h=0 is exactly +0.0 -> skip phase, m=0.0f (bit-exact).
//
// Geometry: 4 batch-groups x 64 col-WGs = 256 WGs x 512 thr (64 b x 8 cols).
// LDS: state [128 r4][64 b][4] = 128 KB; x_t aliased in first 33 KB (stride
// 1040 to de-conflict stage writes), consumed by xh before h-stage overwrites.
// hbuf[2][4][128][64][4] in ws: scatter-write (2 KB/WG), coalesced read,
// b128-LDS-write-ready. W^T[col][640] transposed once per WG (own slice only).
//
// Numerics BIT-IDENTICAL to R9/R15 (absmax 0.125): per (b,c): xh fmaf chain
// ascending k, +b_h, hh chain ascending i, contract(off), Eigen tanh, f64
// ascending head. Only lane assignment and operand routing changed.

#define BATCH   256
#define SEQ     1024
#define IN_DIM  128
#define HIDDEN  512
#define CLASSES 128
#define NWG     256
#define NGRP    4
#define GB      64            // batches per group
#define WCOLS   8             // cols per WG (1 per wave)
#define NRANK   64            // WGs per group
#define WTROWS  (IN_DIM + HIDDEN)   // 640 rows per transposed column

#define XSTRIDE 1040          // bytes per k4-row in LDS x view (pad vs 1024)
#define HSTRIDE 1024          // bytes per r4-row in LDS h view

// ---- Eigen/XLA rational tanh f32, FMA variant — verbatim R5 ----
__device__ __forceinline__ float eigen_tanhf_fma(float ax) {
#pragma clang fp contract(off)
    const float pc = 7.99881172180175781f, mc = -7.99881172180175781f;
    float x = fmaxf(fminf(ax, pc), mc);
    float x2 = x * x;
    float p = __builtin_fmaf(x2, -2.76076847742355e-16f, 2.00018790482477e-13f);
    p = __builtin_fmaf(x2, p, -8.60467152213735e-11f);
    p = __builtin_fmaf(x2, p, 5.12229709037114e-08f);
    p = __builtin_fmaf(x2, p, 1.48572235717979e-05f);
    p = __builtin_fmaf(x2, p, 6.37261928875436e-04f);
    p = __builtin_fmaf(x2, p, 4.89352455891786e-03f);
    p = x * p;
    float q = __builtin_fmaf(x2, 1.19825839466702e-06f, 1.18534705686654e-04f);
    q = __builtin_fmaf(x2, q, 2.26843463243900e-03f);
    q = __builtin_fmaf(x2, q, 4.89352518554385e-03f);
    float r = p / q;
    return (fabsf(ax) < 0.0004f) ? ax : r;
}

__global__ __launch_bounds__(512, 2)
void rnn_fast(const float* __restrict__ x,
              const float* __restrict__ W_hh,
              const float* __restrict__ W_xh,
              const float* __restrict__ W_hy,
              const float* __restrict__ b_h,
              const float* __restrict__ b_y,
              float* __restrict__ out,
              float* wT,                     // [512][640] ws (no restrict: RW)
              float* hbuf,                   // [2][4][128][64][4] ws
              unsigned* flag)                // [4][64] ws, zeroed per launch
{
    __shared__ alignas(16) char lds[131072];   // h view 128 KB; x view aliased

    const int tid  = threadIdx.x;
    const int bid  = blockIdx.x;
    const int g    = bid >> 6;          // batch group 0..3
    const int rank = bid & 63;          // col-WG rank 0..63
    const int lane = tid & 63;          // batch within group
    int col = (rank << 3) + (tid >> 6); // this wave's hidden column
    col = __builtin_amdgcn_readfirstlane(col);   // formally uniform

    // ---- one-time: transpose OWN 8-col slice of [W_xh; W_hh] into wT ----
    {
        const int c0 = rank << 3;
        if (tid < IN_DIM) {
            const int r = tid;
            const float4 u0 = *(const float4*)&W_xh[(size_t)r * HIDDEN + c0];
            const float4 u1 = *(const float4*)&W_xh[(size_t)r * HIDDEN + c0 + 4];
            wT[(size_t)(c0 + 0) * WTROWS + r] = u0.x;
            wT[(size_t)(c0 + 1) * WTROWS + r] = u0.y;
            wT[(size_t)(c0 + 2) * WTROWS + r] = u0.z;
            wT[(size_t)(c0 + 3) * WTROWS + r] = u0.w;
            wT[(size_t)(c0 + 4) * WTROWS + r] = u1.x;
            wT[(size_t)(c0 + 5) * WTROWS + r] = u1.y;
            wT[(size_t)(c0 + 6) * WTROWS + r] = u1.z;
            wT[(size_t)(c0 + 7) * WTROWS + r] = u1.w;
        }
        {
            const int r = tid;   // 512 rows, one per thread
            const float4 u0 = *(const float4*)&W_hh[(size_t)r * HIDDEN + c0];
            const float4 u1 = *(const float4*)&W_hh[(size_t)r * HIDDEN + c0 + 4];
            wT[(size_t)(c0 + 0) * WTROWS + IN_DIM + r] = u0.x;
            wT[(size_t)(c0 + 1) * WTROWS + IN_DIM + r] = u0.y;
            wT[(size_t)(c0 + 2) * WTROWS + IN_DIM + r] = u0.z;
            wT[(size_t)(c0 + 3) * WTROWS + IN_DIM + r] = u0.w;
            wT[(size_t)(c0 + 4) * WTROWS + IN_DIM + r] = u1.x;
            wT[(size_t)(c0 + 5) * WTROWS + IN_DIM + r] = u1.y;
            wT[(size_t)(c0 + 6) * WTROWS + IN_DIM + r] = u1.z;
            wT[(size_t)(c0 + 7) * WTROWS + IN_DIM + r] = u1.w;
        }
        __syncthreads();   // drain stores before first (scalar) wT read
    }

    const float* wcol = wT + (size_t)col * WTROWS;   // uniform base
    const float bh = b_h[col];
    unsigned* gflag = flag + g * NRANK;
    float4* hbuf4 = (float4*)hbuf;

    for (int t = 0; t < SEQ; ++t) {
        // ---- stage x_t: [64 b][128 k] -> LDS x-view [k4][b][4], pad 1040 ----
        {
            const int b = tid >> 3, kq = tid & 7;
            const float* xs = x + ((size_t)(g * GB + b) * SEQ + t) * IN_DIM + kq * 16;
            float4 v0 = *(const float4*)(xs + 0);
            float4 v1 = *(const float4*)(xs + 4);
            float4 v2 = *(const float4*)(xs + 8);
            float4 v3 = *(const float4*)(xs + 12);
            char* xd = lds + (size_t)b * 16;
            *(float4*)(xd + (size_t)(kq * 4 + 0) * XSTRIDE) = v0;
            *(float4*)(xd + (size_t)(kq * 4 + 1) * XSTRIDE) = v1;
            *(float4*)(xd + (size_t)(kq * 4 + 2) * XSTRIDE) = v2;
            *(float4*)(xd + (size_t)(kq * 4 + 3) * XSTRIDE) = v3;
        }
        __syncthreads();

        // ---- xh chain: ascending k, w from scalar pipe, x from LDS ----
        float a;
        {
#pragma clang fp contract(off)
            a = 0.0f;
#pragma unroll 8
            for (int r4 = 0; r4 < IN_DIM / 4; ++r4) {
                const float4 w4 = *(const float4*)(wcol + 4 * r4);
                const float4 x4 = *(const float4*)(lds + (size_t)r4 * XSTRIDE
                                                       + (size_t)lane * 16);
                a = __builtin_fmaf(x4.x, w4.x, a);
                a = __builtin_fmaf(x4.y, w4.y, a);
                a = __builtin_fmaf(x4.z, w4.z, a);
                a = __builtin_fmaf(x4.w, w4.w, a);
            }
            a = a + bh;
        }
        __syncthreads();   // all xh reads done before h-stage overwrites x view

        float m;
        if (t > 0) {
            // ---- wait siblings' h(t): 64 parallel flag spins + 1 acquire ----
            if (tid < 64) {
                const unsigned tgt = (unsigned)t;
                for (;;) {
                    const unsigned v = __hip_atomic_load(&gflag[tid],
                        __ATOMIC_RELAXED, __HIP_MEMORY_SCOPE_AGENT);
                    if (__all(v >= tgt)) break;
                    __builtin_amdgcn_s_sleep(2);
                }
                if (tid == 0)
                    (void)__hip_atomic_load(&gflag[0], __ATOMIC_ACQUIRE,
                                            __HIP_MEMORY_SCOPE_AGENT);
            }
            __syncthreads();

            // ---- stage h(t): coalesced hbuf reads -> linear b128 LDS writes ----
            const float4* hsrc = hbuf4 + ((size_t)((t & 1) * NGRP + g)) * (128 * 64);
#pragma unroll 8
            for (int q = 0; q < 8; ++q) {
                const int slot = q * 512 + tid;
                const float4 v = hsrc[slot];
                *(float4*)(lds + (size_t)slot * 16) = v;
            }
#pragma unroll 8
            for (int q = 8; q < 16; ++q) {
                const int slot = q * 512 + tid;
                const float4 v = hsrc[slot];
                *(float4*)(lds + (size_t)slot * 16) = v;
            }
            __syncthreads();

            // ---- hh chain: ascending i, w scalar, h from LDS ----
            {
#pragma clang fp contract(off)
                m = 0.0f;
                const float* wh = wcol + IN_DIM;
#pragma unroll 8
                for (int r4 = 0; r4 < HIDDEN / 4; ++r4) {
                    const float4 w4 = *(const float4*)(wh + 4 * r4);
                    const float4 h4 = *(const float4*)(lds + (size_t)r4 * HSTRIDE
                                                           + (size_t)lane * 16);
                    m = __builtin_fmaf(h4.x, w4.x, m);
                    m = __builtin_fmaf(h4.y, w4.y, m);
                    m = __builtin_fmaf(h4.z, w4.z, m);
                    m = __builtin_fmaf(h4.w, w4.w, m);
                }
            }
        } else {
            m = 0.0f;   // hh chain over h=0 is exactly +0.0
        }

        // ---- h' = tanh(a+m); publish ----
        const float hv = eigen_tanhf_fma(a + m);
        hbuf[((((size_t)(((t + 1) & 1) * NGRP + g)) * 128 + (col >> 2)) * 64
              + lane) * 4 + (col & 3)] = hv;
        __syncthreads();   // drain WG stores (vmcnt) before release
        if (tid == 0)
            __hip_atomic_store(&gflag[rank], (unsigned)(t + 1),
                               __ATOMIC_RELEASE, __HIP_MEMORY_SCOPE_AGENT);
    }

    // ---- head: wait group h(SEQ), then batch g*64+rank, class tid ----
    if (tid < 64) {
        for (;;) {
            const unsigned v = __hip_atomic_load(&gflag[tid],
                __ATOMIC_RELAXED, __HIP_MEMORY_SCOPE_AGENT);
            if (__all(v >= (unsigned)SEQ)) break;
            __builtin_amdgcn_s_sleep(2);
        }
        if (tid == 0)
            (void)__hip_atomic_load(&gflag[0], __ATOMIC_ACQUIRE,
                                    __HIP_MEMORY_SCOPE_AGENT);
    }
    __syncthreads();

    if (tid < CLASSES) {
        // h(SEQ) at parity 0; f64 ascending chain (same as R9/R15)
        const float* hb = hbuf + ((size_t)g * 128 * 64 * 4);
        double acc = 0.0;
        for (int i = 0; i < HIDDEN; ++i) {
            const float hfv = hb[(((size_t)(i >> 2)) * 64 + rank) * 4 + (i & 3)];
            acc += (double)hfv * (double)W_hy[(size_t)i * CLASSES + tid];
        }
        acc += (double)b_y[tid];
        out[(size_t)(g * GB + rank) * CLASSES + tid] = (float)acc;
    }
}

extern "C" void kernel_launch(void* const* d_in, const int* in_sizes, int n_in,
                              void* d_out, int out_size, void* d_ws, size_t ws_size,
                              hipStream_t stream)
{
    const float *x, *W_hh, *W_xh, *W_hy, *b_h, *b_y;
    if (in_sizes[0] == BATCH * SEQ * IN_DIM) {
        x    = (const float*)d_in[0];
        W_hh = (const float*)d_in[1];
        W_xh = (const float*)d_in[2];
        W_hy = (const float*)d_in[3];
        b_h  = (const float*)d_in[4];
        b_y  = (const float*)d_in[5];
    } else {
        W_hh = (const float*)d_in[0];
        W_hy = (const float*)d_in[1];
        W_xh = (const float*)d_in[2];
        b_h  = (const float*)d_in[3];
        b_y  = (const float*)d_in[4];
        x    = (const float*)d_in[5];
    }
    float* out = (float*)d_out;
    (void)n_in; (void)out_size; (void)ws_size;

    // ws layout: wT 512*640*4 = 1,310,720 | hbuf 2*4*128*64*4*4 = 1,048,576
    //            | flags 4*64*4 = 1,024   (total ~2.25 MB)
    float* wT      = (float*)d_ws;
    float* hbuf    = (float*)((char*)d_ws + 1310720);
    unsigned* flag = (unsigned*)((char*)d_ws + 1310720 + 1048576);

    hipMemsetAsync(flag, 0, NGRP * NRANK * sizeof(unsigned), stream);

    void* args[] = { (void*)&x, (void*)&W_hh, (void*)&W_xh, (void*)&W_hy,
                     (void*)&b_h, (void*)&b_y, (void*)&out,
                     (void*)&wT, (void*)&hbuf, (void*)&flag };
    hipLaunchCooperativeKernel((const void*)rnn_fast, dim3(NWG), dim3(512),
                               args, 0, stream);
}

// Round 8
// 10360.983 us; speedup vs baseline: 1.7723x; 1.7723x over previous
//
#include <hip/hip_runtime.h>
#include <stdint.h>

// VanillaRNN — Round 17: R15 structure + flag exchange + xh-overlapped wait.
//
// R16 post-mortem (18.4 ms): per-step agent-ACQUIRE invalidates local caches
// -> global-resident W (wT) re-missed to L3 every step (FETCH 2.37 GB, VALU
// 13%); lane-stride-16B state reads = 201M bank conflicts. Lessons: W must
// stay in LDS (immune to acquire-inv); keep R15's broadcast/contiguous LDS
// patterns; flag-store exchange itself passed (memory model validated).
//
// R15 (12.64 ms, best): persistent 32-col W slice in LDS, 16-WG clusters,
// h via global hbuf. Cost split: compute+LDS ~1.2 us/step; rest = exchange:
// 16 serialized fetch_adds, convoy wait before xh, x-stage L3 latency.
// R17 fixes exactly those three:
//   1) per-rank RELEASE flag stores (no RMW serialization), 64-lane poll;
//   2) xh chain computed BEFORE the wait (poll overlaps ~1 us of work);
//   3) x_{t+1} prefetched to registers during step t (L3 latency hidden).
//
// Numerics BIT-IDENTICAL to R9/R15 (absmax 0.125): per (b,col): xh fmaf
// chain ascending k=0..127, +b_h, hh chain ascending i=0..511 (one thread
// owns the whole chain), contract(off), verbatim Eigen tanh, f64 ascending
// head. h crosses global as exact f32 bits. t=0: hh over h=0 == +0.0, skip.

#define BATCH   256
#define SEQ     1024
#define IN_DIM  128
#define HIDDEN  512
#define CLASSES 128
#define NWG     256
#define CWGS    16           // WGs per cluster
#define NCL     16           // clusters
#define BPC     16           // batch per cluster
#define COLS    32           // columns per WG
#define NROWS   (IN_DIM + HIDDEN)   // 640

// ---- Eigen/XLA rational tanh f32, FMA variant — verbatim R5 ----
__device__ __forceinline__ float eigen_tanhf_fma(float ax) {
#pragma clang fp contract(off)
    const float pc = 7.99881172180175781f, mc = -7.99881172180175781f;
    float x = fmaxf(fminf(ax, pc), mc);
    float x2 = x * x;
    float p = __builtin_fmaf(x2, -2.76076847742355e-16f, 2.00018790482477e-13f);
    p = __builtin_fmaf(x2, p, -8.60467152213735e-11f);
    p = __builtin_fmaf(x2, p, 5.12229709037114e-08f);
    p = __builtin_fmaf(x2, p, 1.48572235717979e-05f);
    p = __builtin_fmaf(x2, p, 6.37261928875436e-04f);
    p = __builtin_fmaf(x2, p, 4.89352455891786e-03f);
    p = x * p;
    float q = __builtin_fmaf(x2, 1.19825839466702e-06f, 1.18534705686654e-04f);
    q = __builtin_fmaf(x2, q, 2.26843463243900e-03f);
    q = __builtin_fmaf(x2, q, 4.89352518554385e-03f);
    float r = p / q;
    return (fabsf(ax) < 0.0004f) ? ax : r;
}

__global__ __launch_bounds__(512, 2)
void rnn_fast(const float* __restrict__ x,
              const float* __restrict__ W_hh,
              const float* __restrict__ W_xh,
              const float* __restrict__ W_hy,
              const float* __restrict__ b_h,
              const float* __restrict__ b_y,
              float* __restrict__ out,
              unsigned* __restrict__ flag,    // [NCL][CWGS], zeroed per launch
              float* __restrict__ hbuf)       // [2][BATCH][HIDDEN]
{
    // persistent W slice, blocked [row/4][col][4]: a wave's w-read is 4
    // contiguous 256B phases (conflict-free); hb/xb broadcast-read (uniform).
    __shared__ alignas(16) float wq[NROWS / 4][COLS][4];   // 80 KB
    __shared__ alignas(16) float hb[BPC][HIDDEN];          // 32 KB
    __shared__ alignas(16) float xb[BPC][IN_DIM];          //  8 KB

    const int tid = threadIdx.x;
    const int g   = blockIdx.x;
    const int c   = tid & 31;          // column within slice
    const int bb  = tid >> 5;          // batch within cluster (0..15)

    // cluster mapping: siblings stride-8 in blockIdx -> same XCD L2 (heuristic
    // only; correctness is agent-scope). Bijective: g = (cl&7) + 8*((cl>>3)*16+cr).
    const int cl = (g & 7) + ((g >> 7) << 3);   // cluster 0..15
    const int cr = (g >> 3) & 15;               // rank in cluster 0..15
    const int bbase = cl << 4;                  // first batch of cluster
    const int col   = (cr << 5) + c;            // this thread's hidden column

    const float bh = b_h[col];
    unsigned* cflag = flag + cl * CWGS;
    const float4* wbase = (const float4*)wq + c;   // wq[r4][c][0..3] = wbase[r4*32]

    // ---- one-time: W slice -> LDS (640 rows x 32 cols) ----
    for (int pass = 0; pass < NROWS / 16; ++pass) {
        const int r = pass * 16 + bb;
        const float v = (r < IN_DIM)
            ? W_xh[(size_t)r * HIDDEN + col]
            : W_hh[(size_t)(r - IN_DIM) * HIDDEN + col];
        wq[r >> 2][c][r & 3] = v;
    }
    // h_0 = 0
#pragma unroll
    for (int p = 0; p < 4; ++p)
        *(float4*)&hb[bb][c * 4 + p * 128] = make_float4(0.f, 0.f, 0.f, 0.f);

    // x_0 prefetch: thread (bx, k4) owns x[bbase+bx][t][4k4..4k4+3]
    const int bx = tid >> 5, k4 = tid & 31;
    const float* pxt = x + (size_t)(bbase + bx) * SEQ * IN_DIM + k4 * 4;
    float4 xreg = *(const float4*)pxt;
    __syncthreads();

    for (int t = 0; t < SEQ; ++t) {
        // ---- x_t: reg -> LDS (WAR vs last step's xh reads: publish sync) ----
        *(float4*)&xb[bx][k4 * 4] = xreg;
        __syncthreads();

        // ---- xh chain: ascending k; w contiguous-phase LDS, x broadcast ----
        float a;
        {
#pragma clang fp contract(off)
            a = 0.0f;
            const float4* xrow = (const float4*)&xb[bb][0];
#pragma unroll 8
            for (int r4 = 0; r4 < IN_DIM / 4; ++r4) {
                const float4 w4 = wbase[r4 * 32];
                const float4 x4 = xrow[r4];
                a = __builtin_fmaf(x4.x, w4.x, a);
                a = __builtin_fmaf(x4.y, w4.y, a);
                a = __builtin_fmaf(x4.z, w4.z, a);
                a = __builtin_fmaf(x4.w, w4.w, a);
            }
            a = a + bh;
        }

        // ---- prefetch x_{t+1} (in flight across the poll) ----
        if (t + 1 < SEQ)
            xreg = *(const float4*)(pxt + (size_t)(t + 1) * IN_DIM);

        float m;
        if (t > 0) {
            // ---- wait siblings' h(t): wave0 polls 16 flags in parallel ----
            if (tid < 64) {
                const unsigned tgt = (unsigned)t;
                for (;;) {
                    const unsigned v = __hip_atomic_load(&cflag[tid & 15],
                        __ATOMIC_RELAXED, __HIP_MEMORY_SCOPE_AGENT);
                    if (__all(v >= tgt)) break;
                    __builtin_amdgcn_s_sleep(1);
                }
                if (tid == 0)
                    (void)__hip_atomic_load(&cflag[0], __ATOMIC_ACQUIRE,
                                            __HIP_MEMORY_SCOPE_AGENT);
            }
            __syncthreads();   // publish acquired view to whole WG

            // ---- stage h(t): coalesced hbuf reads -> LDS (parity t&1) ----
            const float* hsrc = hbuf + ((size_t)(t & 1) * BATCH + bbase) * HIDDEN;
#pragma unroll
            for (int p = 0; p < 4; ++p) {
                const int slot = p * 512 + tid;   // over 16*512 floats /4
                ((float4*)hb)[slot] = ((const float4*)hsrc)[slot];
            }
            __syncthreads();

            // ---- hh chain: ascending i; w contiguous LDS, h broadcast ----
            {
#pragma clang fp contract(off)
                m = 0.0f;
                const float4* hrow = (const float4*)&hb[bb][0];
#pragma unroll 8
                for (int r4 = 0; r4 < HIDDEN / 4; ++r4) {
                    const float4 w4 = wbase[(IN_DIM / 4 + r4) * 32];
                    const float4 h4 = hrow[r4];
                    m = __builtin_fmaf(h4.x, w4.x, m);
                    m = __builtin_fmaf(h4.y, w4.y, m);
                    m = __builtin_fmaf(h4.z, w4.z, m);
                    m = __builtin_fmaf(h4.w, w4.w, m);
                }
            }
        } else {
            m = 0.0f;   // hh chain over h=0 is exactly +0.0
        }

        // ---- h' = tanh(a+m); publish to other parity; release ----
        const float hnew = eigen_tanhf_fma(a + m);
        hbuf[((size_t)((t + 1) & 1) * BATCH + (bbase + bb)) * HIDDEN + col] = hnew;
        __syncthreads();   // drains every thread's store (vmcnt 0)
        if (tid == 0)
            __hip_atomic_store(&cflag[cr], (unsigned)(t + 1),
                               __ATOMIC_RELEASE, __HIP_MEMORY_SCOPE_AGENT);
    }

    // ---- head: wait cluster h(SEQ); batch bbase+cr, class tid (f64 asc) ----
    if (tid < 64) {
        for (;;) {
            const unsigned v = __hip_atomic_load(&cflag[tid & 15],
                __ATOMIC_RELAXED, __HIP_MEMORY_SCOPE_AGENT);
            if (__all(v >= (unsigned)SEQ)) break;
            __builtin_amdgcn_s_sleep(1);
        }
        if (tid == 0)
            (void)__hip_atomic_load(&cflag[0], __ATOMIC_ACQUIRE,
                                    __HIP_MEMORY_SCOPE_AGENT);
    }
    __syncthreads();

    if (tid < CLASSES) {
        const int bfin = bbase + cr;
        const float* hf = hbuf + (size_t)bfin * HIDDEN;   // parity 0 (SEQ even)
        double acc = 0.0;
        for (int i = 0; i < HIDDEN; ++i) {
            acc += (double)hf[i] * (double)W_hy[(size_t)i * CLASSES + tid];
        }
        acc += (double)b_y[tid];
        out[(size_t)bfin * CLASSES + tid] = (float)acc;
    }
}

extern "C" void kernel_launch(void* const* d_in, const int* in_sizes, int n_in,
                              void* d_out, int out_size, void* d_ws, size_t ws_size,
                              hipStream_t stream)
{
    const float *x, *W_hh, *W_xh, *W_hy, *b_h, *b_y;
    if (in_sizes[0] == BATCH * SEQ * IN_DIM) {
        x    = (const float*)d_in[0];
        W_hh = (const float*)d_in[1];
        W_xh = (const float*)d_in[2];
        W_hy = (const float*)d_in[3];
        b_h  = (const float*)d_in[4];
        b_y  = (const float*)d_in[5];
    } else {
        W_hh = (const float*)d_in[0];
        W_hy = (const float*)d_in[1];
        W_xh = (const float*)d_in[2];
        b_h  = (const float*)d_in[3];
        b_y  = (const float*)d_in[4];
        x    = (const float*)d_in[5];
    }
    float* out = (float*)d_out;
    (void)n_in; (void)out_size; (void)ws_size;

    // ws layout: flags NCL*CWGS u32 = 1 KB | hbuf 2*256*512 f32 = 1 MB
    unsigned* flag = (unsigned*)d_ws;
    float* hbuf    = (float*)((char*)d_ws + 4096);

    hipMemsetAsync(flag, 0, NCL * CWGS * sizeof(unsigned), stream);

    void* args[] = { (void*)&x, (void*)&W_hh, (void*)&W_xh, (void*)&W_hy,
                     (void*)&b_h, (void*)&b_y, (void*)&out,
                     (void*)&flag, (void*)&hbuf };
    hipLaunchCooperativeKernel((const void*)rnn_fast, dim3(NWG), dim3(512),
                               args, 0, stream);
}

// Round 9
// 8025.711 us; speedup vs baseline: 2.2879x; 1.2910x over previous
//
#include <hip/hip_runtime.h>
#include <stdint.h>

// VanillaRNN — Round 18: fence-free exchange (atomic-payload h), R17 otherwise.
//
// R17 (10.36 ms): persistent-W LDS + flag exchange + overlap. Decomposition:
// compute ~1.3 us/step; ~9 us = exchange. New theory: per-step agent-scope
// RELEASE/ACQUIRE compile to buffer_wbl2 / buffer_inv (per-XCD L2 is non-
// coherent -> fences must write-back/invalidate L2) — a full L2 maintenance
// pair per WG per step, 16 WGs per L2. Explains R15/R17 floor and R16's
// global-W death (inv evicted it every step).
//
// R18 changes ONLY the exchange: h values cross WGs as RELAXED agent-scope
// u64 atomics (uncached, complete at the coherence point; bypass L1/L2 on
// read -> always fresh). Producer order: atomic data stores -> __syncthreads
// (implicit per-thread vmcnt(0) drain = completion) -> relaxed flag store.
// Consumer: relaxed flag poll -> relaxed atomic data loads. NO release, NO
// acquire, NO wbl2/inv anywhere in the loop. x-prefetch lines now also
// survive in L2 (no per-step invalidation).
//
// Numerics BIT-IDENTICAL to R9/R15/R17 (absmax 0.125): per (b,col): xh fmaf
// chain ascending k=0..127, +b_h, hh chain ascending i=0..511, contract(off),
// verbatim Eigen tanh, f64 ascending head. h crosses as exact f32 bits.

#define BATCH   256
#define SEQ     1024
#define IN_DIM  128
#define HIDDEN  512
#define CLASSES 128
#define NWG     256
#define CWGS    16           // WGs per cluster
#define NCL     16           // clusters
#define BPC     16           // batch per cluster
#define COLS    32           // columns per WG
#define NROWS   (IN_DIM + HIDDEN)   // 640

typedef unsigned long long ull;
union F2U { float f[2]; ull u; };

// ---- Eigen/XLA rational tanh f32, FMA variant — verbatim R5 ----
__device__ __forceinline__ float eigen_tanhf_fma(float ax) {
#pragma clang fp contract(off)
    const float pc = 7.99881172180175781f, mc = -7.99881172180175781f;
    float x = fmaxf(fminf(ax, pc), mc);
    float x2 = x * x;
    float p = __builtin_fmaf(x2, -2.76076847742355e-16f, 2.00018790482477e-13f);
    p = __builtin_fmaf(x2, p, -8.60467152213735e-11f);
    p = __builtin_fmaf(x2, p, 5.12229709037114e-08f);
    p = __builtin_fmaf(x2, p, 1.48572235717979e-05f);
    p = __builtin_fmaf(x2, p, 6.37261928875436e-04f);
    p = __builtin_fmaf(x2, p, 4.89352455891786e-03f);
    p = x * p;
    float q = __builtin_fmaf(x2, 1.19825839466702e-06f, 1.18534705686654e-04f);
    q = __builtin_fmaf(x2, q, 2.26843463243900e-03f);
    q = __builtin_fmaf(x2, q, 4.89352518554385e-03f);
    float r = p / q;
    return (fabsf(ax) < 0.0004f) ? ax : r;
}

__global__ __launch_bounds__(512, 2)
void rnn_fast(const float* __restrict__ x,
              const float* __restrict__ W_hh,
              const float* __restrict__ W_xh,
              const float* __restrict__ W_hy,
              const float* __restrict__ b_h,
              const float* __restrict__ b_y,
              float* __restrict__ out,
              unsigned* __restrict__ flag,    // [NCL][CWGS], zeroed per launch
              float* __restrict__ hbuf)       // [2][BATCH][HIDDEN], atomic-only
{
    __shared__ alignas(16) float wq[NROWS / 4][COLS][4];   // 80 KB persistent W
    __shared__ alignas(16) float hb[BPC][HIDDEN];          // 32 KB
    __shared__ alignas(16) float xb[BPC][IN_DIM];          //  8 KB

    const int tid = threadIdx.x;
    const int g   = blockIdx.x;
    const int c   = tid & 31;          // column within slice
    const int bb  = tid >> 5;          // batch within cluster (0..15)

    const int cl = (g & 7) + ((g >> 7) << 3);   // cluster 0..15
    const int cr = (g >> 3) & 15;               // rank in cluster 0..15
    const int bbase = cl << 4;                  // first batch of cluster
    const int col   = (cr << 5) + c;            // this thread's hidden column

    const float bh = b_h[col];
    unsigned* cflag = flag + cl * CWGS;
    const float4* wbase = (const float4*)wq + c;

    // ---- one-time: W slice -> LDS (640 rows x 32 cols) ----
    for (int pass = 0; pass < NROWS / 16; ++pass) {
        const int r = pass * 16 + bb;
        const float v = (r < IN_DIM)
            ? W_xh[(size_t)r * HIDDEN + col]
            : W_hh[(size_t)(r - IN_DIM) * HIDDEN + col];
        wq[r >> 2][c][r & 3] = v;
    }

    // x_0 prefetch: thread (bx, k4) owns x[bbase+bx][t][4k4..4k4+3]
    const int bx = tid >> 5, k4 = tid & 31;
    const float* pxt = x + (size_t)(bbase + bx) * SEQ * IN_DIM + k4 * 4;
    float4 xreg = *(const float4*)pxt;
    __syncthreads();

    for (int t = 0; t < SEQ; ++t) {
        // ---- x_t: reg -> LDS ----
        *(float4*)&xb[bx][k4 * 4] = xreg;
        __syncthreads();

        // ---- xh chain: ascending k; w contiguous-phase LDS, x broadcast ----
        float a;
        {
#pragma clang fp contract(off)
            a = 0.0f;
            const float4* xrow = (const float4*)&xb[bb][0];
#pragma unroll 8
            for (int r4 = 0; r4 < IN_DIM / 4; ++r4) {
                const float4 w4 = wbase[r4 * 32];
                const float4 x4 = xrow[r4];
                a = __builtin_fmaf(x4.x, w4.x, a);
                a = __builtin_fmaf(x4.y, w4.y, a);
                a = __builtin_fmaf(x4.z, w4.z, a);
                a = __builtin_fmaf(x4.w, w4.w, a);
            }
            a = a + bh;
        }

        // ---- prefetch x_{t+1} (plain cached; survives — no inv anymore) ----
        if (t + 1 < SEQ)
            xreg = *(const float4*)(pxt + (size_t)(t + 1) * IN_DIM);

        float m;
        if (t > 0) {
            // ---- wait siblings' h(t): relaxed poll, NO acquire ----
            if (tid < 64) {
                const unsigned tgt = (unsigned)t;
                for (;;) {
                    const unsigned v = __hip_atomic_load(&cflag[tid & 15],
                        __ATOMIC_RELAXED, __HIP_MEMORY_SCOPE_AGENT);
                    if (__all(v >= tgt)) break;
                    __builtin_amdgcn_s_sleep(1);
                }
            }
            __syncthreads();

            // ---- stage h(t): relaxed atomic u64 loads (bypass caches) ----
            const ull* hsrc8 = (const ull*)(hbuf
                + ((size_t)(t & 1) * BATCH + bbase) * HIDDEN);
            ull* hdst8 = (ull*)&hb[0][0];
#pragma unroll
            for (int q = 0; q < 8; ++q) {
                const int p = q * 512 + tid;   // u64 pair index, 0..4095
                hdst8[p] = __hip_atomic_load(hsrc8 + p, __ATOMIC_RELAXED,
                                             __HIP_MEMORY_SCOPE_AGENT);
            }
            __syncthreads();

            // ---- hh chain: ascending i; w contiguous LDS, h broadcast ----
            {
#pragma clang fp contract(off)
                m = 0.0f;
                const float4* hrow = (const float4*)&hb[bb][0];
#pragma unroll 8
                for (int r4 = 0; r4 < HIDDEN / 4; ++r4) {
                    const float4 w4 = wbase[(IN_DIM / 4 + r4) * 32];
                    const float4 h4 = hrow[r4];
                    m = __builtin_fmaf(h4.x, w4.x, m);
                    m = __builtin_fmaf(h4.y, w4.y, m);
                    m = __builtin_fmaf(h4.z, w4.z, m);
                    m = __builtin_fmaf(h4.w, w4.w, m);
                }
            }
        } else {
            m = 0.0f;   // hh chain over h=0 is exactly +0.0
        }

        // ---- h' = tanh(a+m); publish via relaxed atomic u64 stores ----
        const float hnew = eigen_tanhf_fma(a + m);
        const float hnb  = __shfl_xor(hnew, 1);   // neighbor column's h
        if ((c & 1) == 0) {
            F2U u; u.f[0] = hnew; u.f[1] = hnb;   // cols col, col+1
            ull* dst = (ull*)&hbuf[((size_t)((t + 1) & 1) * BATCH
                                    + (bbase + bb)) * HIDDEN + col];
            __hip_atomic_store(dst, u.u, __ATOMIC_RELAXED,
                               __HIP_MEMORY_SCOPE_AGENT);
        }
        __syncthreads();   // per-thread vmcnt(0) drain: stores completed at
                           // the coherence point before the flag goes out
        if (tid == 0)
            __hip_atomic_store(&cflag[cr], (unsigned)(t + 1),
                               __ATOMIC_RELAXED, __HIP_MEMORY_SCOPE_AGENT);
    }

    // ---- head: wait cluster h(SEQ); stage via atomics; f64 ascending ----
    if (tid < 64) {
        for (;;) {
            const unsigned v = __hip_atomic_load(&cflag[tid & 15],
                __ATOMIC_RELAXED, __HIP_MEMORY_SCOPE_AGENT);
            if (__all(v >= (unsigned)SEQ)) break;
            __builtin_amdgcn_s_sleep(1);
        }
    }
    __syncthreads();
    {
        // h(SEQ) lives at parity 0 (SEQ even)
        const ull* hsrc8 = (const ull*)(hbuf + (size_t)bbase * HIDDEN);
        ull* hdst8 = (ull*)&hb[0][0];
#pragma unroll
        for (int q = 0; q < 8; ++q) {
            const int p = q * 512 + tid;
            hdst8[p] = __hip_atomic_load(hsrc8 + p, __ATOMIC_RELAXED,
                                         __HIP_MEMORY_SCOPE_AGENT);
        }
    }
    __syncthreads();

    if (tid < CLASSES) {
        const int bfin = bbase + cr;
        double acc = 0.0;
        for (int i = 0; i < HIDDEN; ++i) {
            acc += (double)hb[cr][i] * (double)W_hy[(size_t)i * CLASSES + tid];
        }
        acc += (double)b_y[tid];
        out[(size_t)bfin * CLASSES + tid] = (float)acc;
    }
}

extern "C" void kernel_launch(void* const* d_in, const int* in_sizes, int n_in,
                              void* d_out, int out_size, void* d_ws, size_t ws_size,
                              hipStream_t stream)
{
    const float *x, *W_hh, *W_xh, *W_hy, *b_h, *b_y;
    if (in_sizes[0] == BATCH * SEQ * IN_DIM) {
        x    = (const float*)d_in[0];
        W_hh = (const float*)d_in[1];
        W_xh = (const float*)d_in[2];
        W_hy = (const float*)d_in[3];
        b_h  = (const float*)d_in[4];
        b_y  = (const float*)d_in[5];
    } else {
        W_hh = (const float*)d_in[0];
        W_hy = (const float*)d_in[1];
        W_xh = (const float*)d_in[2];
        b_h  = (const float*)d_in[3];
        b_y  = (const float*)d_in[4];
        x    = (const float*)d_in[5];
    }
    float* out = (float*)d_out;
    (void)n_in; (void)out_size; (void)ws_size;

    // ws layout: flags NCL*CWGS u32 (4KB-aligned block) | hbuf 2*256*512 f32
    unsigned* flag = (unsigned*)d_ws;
    float* hbuf    = (float*)((char*)d_ws + 4096);

    hipMemsetAsync(flag, 0, NCL * CWGS * sizeof(unsigned), stream);

    void* args[] = { (void*)&x, (void*)&W_hh, (void*)&W_xh, (void*)&W_hy,
                     (void*)&b_h, (void*)&b_y, (void*)&out,
                     (void*)&flag, (void*)&hbuf };
    hipLaunchCooperativeKernel((const void*)rnn_fast, dim3(NWG), dim3(512),
                               args, 0, stream);
}